// Round 2
// baseline (3193.726 us; speedup 1.0000x reference)
//
#include <hip/hip_runtime.h>
#include <stdint.h>

// ---------------------------------------------------------------------------
// ImageFeatureEncoder: 3 x (GAT over fully-connected 4-node graph + LN + FFN)
// B=16384, N=4, H=768, HEADS=4, OUT=192, L=3.
// Strategy: bf16 MFMA GEMMs (m97 128x128 structure) + fused rowwise kernels.
// R1: __bf16 frags (matches LLVM V8y builtin sig), g_f32 aliased onto d_out
//     (ws 721->520MB), transposes batched over L via blockIdx.z.
// ---------------------------------------------------------------------------

typedef __bf16 bf16x8 __attribute__((ext_vector_type(8)));
typedef float  f32x4  __attribute__((ext_vector_type(4)));

__device__ __forceinline__ uint16_t f2bf(float f) {
  union { float f; uint32_t u; } v; v.f = f;
  uint32_t r = v.u + 0x7fffu + ((v.u >> 16) & 1u);   // RNE
  return (uint16_t)(r >> 16);
}

__device__ __forceinline__ float wave_sum(float v) {
#pragma unroll
  for (int off = 32; off > 0; off >>= 1) v += __shfl_xor(v, off);
  return v;
}

__device__ __forceinline__ void gload_lds16(const void* g, void* l) {
  __builtin_amdgcn_global_load_lds(
      (const __attribute__((address_space(1))) void*)(g),
      (__attribute__((address_space(3))) void*)(l), 16, 0, 0);
}

// ---------------------------------------------------------------------------
// GEMM: C[M,N] = A[M,K](bf16, row-major) * Bt[N,K](bf16, row-major = B^T)
// EPI 0: C float = acc + bias (bias may be null)
// EPI 1: C bf16 = relu(acc + bias)
// 128x128 tile, BK=32, 4 waves (2x2), 4x4 frags of 16x16x32 per wave.
// ---------------------------------------------------------------------------
template <int EPI>
__global__ __launch_bounds__(256, 2)
void gemm_bf16(const uint16_t* __restrict__ A, const uint16_t* __restrict__ Bt,
               const float* __restrict__ bias, void* __restrict__ Cv,
               int M, int N, int K) {
  __shared__ uint16_t As[128 * 32];
  __shared__ uint16_t Bs[128 * 32];
  const int bn = blockIdx.x, bm = blockIdx.y;  // N-tiles fast -> L3 catches A
  const int t = threadIdx.x;
  const int w = t >> 6, lane = t & 63;
  const int wr = w >> 1, wc = w & 1;

  f32x4 acc[4][4] = {};

  // staging: thread t loads 8 bf16 (16B). Wave w covers LDS rows [w*16,w*16+16)
  // (lane l -> row w*16+(l>>2), col (l&3)*8) == linear bytes w*1024 + l*16,
  // exactly global_load_lds's wave-uniform-base + lane*16 rule.
  const int srow = t >> 2;            // 0..63
  const int scol = (t & 3) * 8;       // 0,8,16,24
  const uint16_t* Ag = A  + (size_t)(bm * 128 + srow) * K + scol;
  const uint16_t* Bg = Bt + (size_t)(bn * 128 + srow) * K + scol;

  const int KT = K >> 5;
  for (int kt = 0; kt < KT; ++kt) {
    __syncthreads();  // previous iter's LDS reads done
    gload_lds16(Ag,          &As[w * 512]);
    gload_lds16(Ag + 64 * K, &As[2048 + w * 512]);
    gload_lds16(Bg,          &Bs[w * 512]);
    gload_lds16(Bg + 64 * K, &Bs[2048 + w * 512]);
    Ag += 32; Bg += 32;
    asm volatile("s_waitcnt vmcnt(0)" ::: "memory");
    __syncthreads();  // staging visible to all waves

    const int fr = lane & 15;
    const int kg = (lane >> 4) * 8;
    bf16x8 a[4], b[4];
#pragma unroll
    for (int m = 0; m < 4; ++m)
      a[m] = *(const bf16x8*)&As[(wr * 64 + m * 16 + fr) * 32 + kg];
#pragma unroll
    for (int n = 0; n < 4; ++n)
      b[n] = *(const bf16x8*)&Bs[(wc * 64 + n * 16 + fr) * 32 + kg];
#pragma unroll
    for (int m = 0; m < 4; ++m)
#pragma unroll
      for (int n = 0; n < 4; ++n)
        acc[m][n] = __builtin_amdgcn_mfma_f32_16x16x32_bf16(a[m], b[n], acc[m][n], 0, 0, 0);
  }

  // epilogue: C/D layout col=lane&15, row=(lane>>4)*4+j  [m89/m91-verified]
  const int row0 = bm * 128 + wr * 64 + ((lane >> 4) * 4);
  const int col0 = bn * 128 + wc * 64 + (lane & 15);
#pragma unroll
  for (int m = 0; m < 4; ++m) {
#pragma unroll
    for (int n = 0; n < 4; ++n) {
      const int col = col0 + n * 16;
      const float bv = bias ? bias[col] : 0.0f;
#pragma unroll
      for (int j = 0; j < 4; ++j) {
        const int row = row0 + m * 16 + j;
        const float v = acc[m][n][j] + bv;
        if (EPI == 0) ((float*)Cv)[(size_t)row * N + col] = v;
        else ((uint16_t*)Cv)[(size_t)row * N + col] = f2bf(fmaxf(v, 0.0f));
      }
    }
  }
}

// ---------------------------------------------------------------------------
// Weight prep: Wt[l][C][R] = bf16(W[l][R][C]); layers batched via blockIdx.z
// ---------------------------------------------------------------------------
__global__ __launch_bounds__(256)
void transpose_f32_to_bf16(const float* __restrict__ W, uint16_t* __restrict__ Wt,
                           int R, int C) {
  __shared__ float tile[32][33];
  const size_t lofs = (size_t)blockIdx.z * R * C;
  W += lofs; Wt += lofs;
  const int c0 = blockIdx.x * 32, r0 = blockIdx.y * 32;
  const int t = threadIdx.x, tc = t & 31, tr = t >> 5;  // tr 0..7
#pragma unroll
  for (int i = 0; i < 4; ++i)
    tile[tr + i * 8][tc] = W[(size_t)(r0 + tr + i * 8) * C + c0 + tc];
  __syncthreads();
#pragma unroll
  for (int i = 0; i < 4; ++i)
    Wt[(size_t)(c0 + tr + i * 8) * R + r0 + tc] = f2bf(tile[tc][tr + i * 8]);
}

// ---------------------------------------------------------------------------
// x = image_features + type_emb ; write f32 and bf16 copies
// ---------------------------------------------------------------------------
__global__ __launch_bounds__(256)
void init_x(const float* __restrict__ img, const float* __restrict__ te,
            float* __restrict__ xout, uint16_t* __restrict__ xb, int n4) {
  for (int i = blockIdx.x * 256 + threadIdx.x; i < n4; i += gridDim.x * 256) {
    const float4 a = ((const float4*)img)[i];
    const float4 b = ((const float4*)te)[i % 768];  // te = 3072 floats = 768 float4
    float4 o; o.x = a.x + b.x; o.y = a.y + b.y; o.z = a.z + b.z; o.w = a.w + b.w;
    ((float4*)xout)[i] = o;
    ushort4 p; p.x = f2bf(o.x); p.y = f2bf(o.y); p.z = f2bf(o.z); p.w = f2bf(o.w);
    ((ushort4*)xb)[i] = p;
  }
}

// ---------------------------------------------------------------------------
// GAT attention (dense 4-node graph) + gat_bias + residual + LayerNorm.
// One block per batch element b. Wave w owns node w.
// ---------------------------------------------------------------------------
__global__ __launch_bounds__(256, 4)
void gat_attn_ln(const float* __restrict__ h, const float* __restrict__ xres,
                 const float* __restrict__ att_src, const float* __restrict__ att_dst,
                 const float* __restrict__ gbias, const float* __restrict__ gamma,
                 const float* __restrict__ beta, float* __restrict__ xout,
                 uint16_t* __restrict__ xb) {
  __shared__ float hs[4 * 768];
  __shared__ float as_[4][4], ad_[4][4];     // [node][head]
  __shared__ float alpha[4][4][4];           // [i][head][j]
  const int b = blockIdx.x;
  const int t = threadIdx.x, w = t >> 6, lane = t & 63;
  const size_t base = (size_t)b * 3072;

  {  // load h[b] : 3072 floats = 768 float4
    const float4* hg = (const float4*)(h + base);
    float4* hl = (float4*)hs;
    for (int i = t; i < 768; i += 256) hl[i] = hg[i];
  }
  __syncthreads();

  {  // per-node, per-head attention dots (length-192 each)
    const int n = w;
#pragma unroll
    for (int hd = 0; hd < 4; ++hd) {
      float ps = 0.f, pd = 0.f;
      for (int d = lane; d < 192; d += 64) {
        const float hv = hs[n * 768 + hd * 192 + d];
        ps += hv * att_src[hd * 192 + d];
        pd += hv * att_dst[hd * 192 + d];
      }
      ps = wave_sum(ps); pd = wave_sum(pd);
      if (lane == 0) { as_[n][hd] = ps; ad_[n][hd] = pd; }
    }
  }
  __syncthreads();

  if (t < 16) {  // alpha[i][hd][:] = softmax_j(leaky_relu(a_d[i]+a_s[j], 0.2))
    const int i = t >> 2, hd = t & 3;
    float e[4], mx = -1e30f;
#pragma unroll
    for (int j = 0; j < 4; ++j) {
      float v = ad_[i][hd] + as_[j][hd];
      v = v > 0.f ? v : 0.2f * v;
      e[j] = v; mx = fmaxf(mx, v);
    }
    float s = 0.f;
#pragma unroll
    for (int j = 0; j < 4; ++j) { e[j] = __expf(e[j] - mx); s += e[j]; }
    const float inv = 1.0f / s;
#pragma unroll
    for (int j = 0; j < 4; ++j) alpha[i][hd][j] = e[j] * inv;
  }
  __syncthreads();

  // aggregate + gat_bias + residual, then LayerNorm over 768 (wave-local)
  const int i = w;
  float v[12];
  float mean = 0.f;
#pragma unroll
  for (int c0 = 0; c0 < 12; ++c0) {
    const int c = c0 * 64 + lane;
    const int hd = c / 192;
    float o = alpha[i][hd][0] * hs[c]        + alpha[i][hd][1] * hs[768 + c] +
              alpha[i][hd][2] * hs[1536 + c] + alpha[i][hd][3] * hs[2304 + c];
    o += gbias[c] + xres[base + i * 768 + c];
    v[c0] = o; mean += o;
  }
  mean = wave_sum(mean) * (1.0f / 768.0f);
  float var = 0.f;
#pragma unroll
  for (int c0 = 0; c0 < 12; ++c0) { const float d = v[c0] - mean; var += d * d; }
  var = wave_sum(var) * (1.0f / 768.0f);
  const float inv = rsqrtf(var + 1e-5f);
#pragma unroll
  for (int c0 = 0; c0 < 12; ++c0) {
    const int c = c0 * 64 + lane;
    const float y = (v[c0] - mean) * inv * gamma[c] + beta[c];
    const size_t idx = base + i * 768 + c;
    xout[idx] = y;
    xb[idx] = f2bf(y);
  }
}

// ---------------------------------------------------------------------------
// x = LN(ffn + x). One wave per row (768). Optionally emit bf16 copy.
// Safe when ffn aliases xout (per-thread read-before-write, same indices).
// ---------------------------------------------------------------------------
__global__ __launch_bounds__(256, 4)
void ffn_ln(const float* __restrict__ ffn, const float* __restrict__ xres,
            const float* __restrict__ gamma, const float* __restrict__ beta,
            float* __restrict__ xout, uint16_t* __restrict__ xb, int write_xb) {
  const int t = threadIdx.x, w = t >> 6, lane = t & 63;
  const size_t row = (size_t)blockIdx.x * 4 + w;
  const size_t base = row * 768;
  const float4* fg = (const float4*)(ffn + base);
  const float4* xg = (const float4*)(xres + base);
  float4 v[3];
  float mean = 0.f;
#pragma unroll
  for (int k = 0; k < 3; ++k) {
    const int i = k * 64 + lane;
    const float4 a = fg[i], b = xg[i];
    v[k].x = a.x + b.x; v[k].y = a.y + b.y; v[k].z = a.z + b.z; v[k].w = a.w + b.w;
    mean += v[k].x + v[k].y + v[k].z + v[k].w;
  }
  mean = wave_sum(mean) * (1.0f / 768.0f);
  float var = 0.f;
#pragma unroll
  for (int k = 0; k < 3; ++k) {
    const float dx = v[k].x - mean, dy = v[k].y - mean;
    const float dz = v[k].z - mean, dw = v[k].w - mean;
    var += dx * dx + dy * dy + dz * dz + dw * dw;
  }
  var = wave_sum(var) * (1.0f / 768.0f);
  const float inv = rsqrtf(var + 1e-5f);
#pragma unroll
  for (int k = 0; k < 3; ++k) {
    const int i = k * 64 + lane;
    const float4 g = ((const float4*)gamma)[i], bb = ((const float4*)beta)[i];
    float4 y;
    y.x = (v[k].x - mean) * inv * g.x + bb.x;
    y.y = (v[k].y - mean) * inv * g.y + bb.y;
    y.z = (v[k].z - mean) * inv * g.z + bb.z;
    y.w = (v[k].w - mean) * inv * g.w + bb.w;
    ((float4*)(xout + base))[i] = y;
    if (write_xb) {
      ushort4 p; p.x = f2bf(y.x); p.y = f2bf(y.y); p.z = f2bf(y.z); p.w = f2bf(y.w);
      ((ushort4*)(xb + base))[i] = p;
    }
  }
}

// ---------------------------------------------------------------------------
extern "C" void kernel_launch(void* const* d_in, const int* in_sizes, int n_in,
                              void* d_out, int out_size, void* d_ws, size_t ws_size,
                              hipStream_t stream) {
  const float* img   = (const float*)d_in[0];
  const float* te    = (const float*)d_in[1];
  const float* Wgat  = (const float*)d_in[2];
  const float* asrc  = (const float*)d_in[3];
  const float* adst  = (const float*)d_in[4];
  const float* gbias = (const float*)d_in[5];
  const float* gam   = (const float*)d_in[6];
  const float* bet   = (const float*)d_in[7];
  const float* W1    = (const float*)d_in[8];
  const float* b1    = (const float*)d_in[9];
  const float* W2    = (const float*)d_in[10];
  const float* b2    = (const float*)d_in[11];

  const int B = 16384;
  const size_t ROWS = (size_t)B * 4;        // 65536
  const size_t XE = ROWS * 768;             // 50331648

  // g_f32 (GAT-proj h / FFN output scratch) lives in d_out: the final ffn_ln
  // reads ffn==d_out and writes xout==d_out element-wise (safe), and every
  // earlier use is fully overwritten downstream.
  float* g_f32 = (float*)d_out;

  uint8_t* p = (uint8_t*)d_ws;
  float*    x_f32 = (float*)p;    p += XE * 4;               // 201MB
  uint16_t* xb    = (uint16_t*)p; p += XE * 2;               // 101MB bf16 acts
  uint16_t* mid   = (uint16_t*)p; p += ROWS * 1536 * 2;      // 201MB FFN hidden
  uint16_t* wtg   = (uint16_t*)p; p += (size_t)3 * 768 * 768 * 2;
  uint16_t* wt1   = (uint16_t*)p; p += (size_t)3 * 1536 * 768 * 2;
  uint16_t* wt2   = (uint16_t*)p; p += (size_t)3 * 768 * 1536 * 2;

  // --- per-launch weight prep (small; batched over layers) ---
  transpose_f32_to_bf16<<<dim3(24, 24, 3), 256, 0, stream>>>(Wgat, wtg, 768, 768);
  transpose_f32_to_bf16<<<dim3(48, 24, 3), 256, 0, stream>>>(W1,   wt1, 768, 1536);
  transpose_f32_to_bf16<<<dim3(24, 48, 3), 256, 0, stream>>>(W2,   wt2, 1536, 768);
  init_x<<<2048, 256, 0, stream>>>(img, te, x_f32, xb, (int)(XE / 4));

  for (int l = 0; l < 3; ++l) {
    // h = x @ W_gat[l]   (no bias; GATConv bias applied after aggregation)
    gemm_bf16<0><<<dim3(768 / 128, ROWS / 128), 256, 0, stream>>>(
        xb, wtg + (size_t)l * 768 * 768, nullptr, g_f32, (int)ROWS, 768, 768);
    // attention + gat_bias + residual + LN -> x (f32 + bf16)
    gat_attn_ln<<<B, 256, 0, stream>>>(
        g_f32, x_f32, asrc + l * 768, adst + l * 768, gbias + l * 768,
        gam + l * 768, bet + l * 768, x_f32, xb);
    // mid = relu(x @ W1[l] + b1[l])  (bf16)
    gemm_bf16<1><<<dim3(1536 / 128, ROWS / 128), 256, 0, stream>>>(
        xb, wt1 + (size_t)l * 1536 * 768, b1 + l * 1536, mid, (int)ROWS, 1536, 768);
    // ffn = mid @ W2[l] + b2[l]      (f32)
    gemm_bf16<0><<<dim3(768 / 128, ROWS / 128), 256, 0, stream>>>(
        mid, wt2 + (size_t)l * 768 * 1536, b2 + l * 768, g_f32, (int)ROWS, 768, 1536);
    // x = LN(ffn + x); last layer writes d_out (aliased with g_f32: safe)
    float* xo = (l == 2) ? (float*)d_out : x_f32;
    ffn_ln<<<ROWS / 4, 256, 0, stream>>>(
        g_f32, x_f32, gam + l * 768, bet + l * 768, xo, xb, (l == 2) ? 0 : 1);
  }
}

// Round 3
// 2926.659 us; speedup vs baseline: 1.0913x; 1.0913x over previous
//
#include <hip/hip_runtime.h>
#include <stdint.h>

// ---------------------------------------------------------------------------
// ImageFeatureEncoder: 3 x (GAT over fully-connected 4-node graph + LN + FFN)
// B=16384, N=4, H=768, HEADS=4, OUT=192, L=3.
// Strategy: bf16 MFMA GEMMs (m97 128x128 structure) + fused rowwise kernels.
// R1: __bf16 frags, g_f32 aliased onto d_out, batched transposes.
// R2: T1 chunked XCD swizzle in gemm_bf16 (R1 counters: FETCH 659MB/GEMM =
//     6.6x A-refetch because same-bm blocks round-robin across 8 XCD L2s).
// ---------------------------------------------------------------------------

typedef __bf16 bf16x8 __attribute__((ext_vector_type(8)));
typedef float  f32x4  __attribute__((ext_vector_type(4)));

__device__ __forceinline__ uint16_t f2bf(float f) {
  union { float f; uint32_t u; } v; v.f = f;
  uint32_t r = v.u + 0x7fffu + ((v.u >> 16) & 1u);   // RNE
  return (uint16_t)(r >> 16);
}

__device__ __forceinline__ float wave_sum(float v) {
#pragma unroll
  for (int off = 32; off > 0; off >>= 1) v += __shfl_xor(v, off);
  return v;
}

__device__ __forceinline__ void gload_lds16(const void* g, void* l) {
  __builtin_amdgcn_global_load_lds(
      (const __attribute__((address_space(1))) void*)(g),
      (__attribute__((address_space(3))) void*)(l), 16, 0, 0);
}

// ---------------------------------------------------------------------------
// GEMM: C[M,N] = A[M,K](bf16, row-major) * Bt[N,K](bf16, row-major = B^T)
// EPI 0: C float = acc + bias (bias may be null)
// EPI 1: C bf16 = relu(acc + bias)
// 128x128 tile, BK=32, 4 waves (2x2), 4x4 frags of 16x16x32 per wave.
// ---------------------------------------------------------------------------
template <int EPI>
__global__ __launch_bounds__(256, 2)
void gemm_bf16(const uint16_t* __restrict__ A, const uint16_t* __restrict__ Bt,
               const float* __restrict__ bias, void* __restrict__ Cv,
               int M, int N, int K) {
  __shared__ uint16_t As[128 * 32];
  __shared__ uint16_t Bs[128 * 32];

  // T1: chunked XCD swizzle. Dispatch index d lands on XCD d%8; remap so each
  // XCD owns a CONTIGUOUS range of the original (bm-major) linear id -> all
  // blocks sharing an A-panel sit on one XCD and hit its L2. Bijective since
  // every grid here has nwg % 8 == 0.
  int wgid = blockIdx.y * gridDim.x + blockIdx.x;
  const int nwg = gridDim.x * gridDim.y;
  if ((nwg & 7) == 0) wgid = (wgid & 7) * (nwg >> 3) + (wgid >> 3);
  const int bn = wgid % gridDim.x, bm = wgid / gridDim.x;

  const int t = threadIdx.x;
  const int w = t >> 6, lane = t & 63;
  const int wr = w >> 1, wc = w & 1;

  f32x4 acc[4][4] = {};

  // staging: thread t loads 8 bf16 (16B). Wave w covers LDS rows [w*16,w*16+16)
  // == linear bytes w*1024 + lane*16 (global_load_lds wave-uniform-base rule).
  const int srow = t >> 2;            // 0..63
  const int scol = (t & 3) * 8;       // 0,8,16,24
  const uint16_t* Ag = A  + (size_t)(bm * 128 + srow) * K + scol;
  const uint16_t* Bg = Bt + (size_t)(bn * 128 + srow) * K + scol;

  const int KT = K >> 5;
  for (int kt = 0; kt < KT; ++kt) {
    __syncthreads();  // previous iter's LDS reads done
    gload_lds16(Ag,          &As[w * 512]);
    gload_lds16(Ag + 64 * K, &As[2048 + w * 512]);
    gload_lds16(Bg,          &Bs[w * 512]);
    gload_lds16(Bg + 64 * K, &Bs[2048 + w * 512]);
    Ag += 32; Bg += 32;
    asm volatile("s_waitcnt vmcnt(0)" ::: "memory");
    __syncthreads();  // staging visible to all waves

    const int fr = lane & 15;
    const int kg = (lane >> 4) * 8;
    bf16x8 a[4], b[4];
#pragma unroll
    for (int m = 0; m < 4; ++m)
      a[m] = *(const bf16x8*)&As[(wr * 64 + m * 16 + fr) * 32 + kg];
#pragma unroll
    for (int n = 0; n < 4; ++n)
      b[n] = *(const bf16x8*)&Bs[(wc * 64 + n * 16 + fr) * 32 + kg];
#pragma unroll
    for (int m = 0; m < 4; ++m)
#pragma unroll
      for (int n = 0; n < 4; ++n)
        acc[m][n] = __builtin_amdgcn_mfma_f32_16x16x32_bf16(a[m], b[n], acc[m][n], 0, 0, 0);
  }

  // epilogue: C/D layout col=lane&15, row=(lane>>4)*4+j  [m89/m91-verified]
  const int row0 = bm * 128 + wr * 64 + ((lane >> 4) * 4);
  const int col0 = bn * 128 + wc * 64 + (lane & 15);
#pragma unroll
  for (int m = 0; m < 4; ++m) {
#pragma unroll
    for (int n = 0; n < 4; ++n) {
      const int col = col0 + n * 16;
      const float bv = bias ? bias[col] : 0.0f;
#pragma unroll
      for (int j = 0; j < 4; ++j) {
        const int row = row0 + m * 16 + j;
        const float v = acc[m][n][j] + bv;
        if (EPI == 0) ((float*)Cv)[(size_t)row * N + col] = v;
        else ((uint16_t*)Cv)[(size_t)row * N + col] = f2bf(fmaxf(v, 0.0f));
      }
    }
  }
}

// ---------------------------------------------------------------------------
// Weight prep: Wt[l][C][R] = bf16(W[l][R][C]); layers batched via blockIdx.z
// ---------------------------------------------------------------------------
__global__ __launch_bounds__(256)
void transpose_f32_to_bf16(const float* __restrict__ W, uint16_t* __restrict__ Wt,
                           int R, int C) {
  __shared__ float tile[32][33];
  const size_t lofs = (size_t)blockIdx.z * R * C;
  W += lofs; Wt += lofs;
  const int c0 = blockIdx.x * 32, r0 = blockIdx.y * 32;
  const int t = threadIdx.x, tc = t & 31, tr = t >> 5;  // tr 0..7
#pragma unroll
  for (int i = 0; i < 4; ++i)
    tile[tr + i * 8][tc] = W[(size_t)(r0 + tr + i * 8) * C + c0 + tc];
  __syncthreads();
#pragma unroll
  for (int i = 0; i < 4; ++i)
    Wt[(size_t)(c0 + tr + i * 8) * R + r0 + tc] = f2bf(tile[tc][tr + i * 8]);
}

// ---------------------------------------------------------------------------
// x = image_features + type_emb ; write f32 and bf16 copies
// ---------------------------------------------------------------------------
__global__ __launch_bounds__(256)
void init_x(const float* __restrict__ img, const float* __restrict__ te,
            float* __restrict__ xout, uint16_t* __restrict__ xb, int n4) {
  for (int i = blockIdx.x * 256 + threadIdx.x; i < n4; i += gridDim.x * 256) {
    const float4 a = ((const float4*)img)[i];
    const float4 b = ((const float4*)te)[i % 768];  // te = 3072 floats = 768 float4
    float4 o; o.x = a.x + b.x; o.y = a.y + b.y; o.z = a.z + b.z; o.w = a.w + b.w;
    ((float4*)xout)[i] = o;
    ushort4 p; p.x = f2bf(o.x); p.y = f2bf(o.y); p.z = f2bf(o.z); p.w = f2bf(o.w);
    ((ushort4*)xb)[i] = p;
  }
}

// ---------------------------------------------------------------------------
// GAT attention (dense 4-node graph) + gat_bias + residual + LayerNorm.
// One block per batch element b. Wave w owns node w.
// ---------------------------------------------------------------------------
__global__ __launch_bounds__(256, 4)
void gat_attn_ln(const float* __restrict__ h, const float* __restrict__ xres,
                 const float* __restrict__ att_src, const float* __restrict__ att_dst,
                 const float* __restrict__ gbias, const float* __restrict__ gamma,
                 const float* __restrict__ beta, float* __restrict__ xout,
                 uint16_t* __restrict__ xb) {
  __shared__ float hs[4 * 768];
  __shared__ float as_[4][4], ad_[4][4];     // [node][head]
  __shared__ float alpha[4][4][4];           // [i][head][j]
  const int b = blockIdx.x;
  const int t = threadIdx.x, w = t >> 6, lane = t & 63;
  const size_t base = (size_t)b * 3072;

  {  // load h[b] : 3072 floats = 768 float4
    const float4* hg = (const float4*)(h + base);
    float4* hl = (float4*)hs;
    for (int i = t; i < 768; i += 256) hl[i] = hg[i];
  }
  __syncthreads();

  {  // per-node, per-head attention dots (length-192 each)
    const int n = w;
#pragma unroll
    for (int hd = 0; hd < 4; ++hd) {
      float ps = 0.f, pd = 0.f;
      for (int d = lane; d < 192; d += 64) {
        const float hv = hs[n * 768 + hd * 192 + d];
        ps += hv * att_src[hd * 192 + d];
        pd += hv * att_dst[hd * 192 + d];
      }
      ps = wave_sum(ps); pd = wave_sum(pd);
      if (lane == 0) { as_[n][hd] = ps; ad_[n][hd] = pd; }
    }
  }
  __syncthreads();

  if (t < 16) {  // alpha[i][hd][:] = softmax_j(leaky_relu(a_d[i]+a_s[j], 0.2))
    const int i = t >> 2, hd = t & 3;
    float e[4], mx = -1e30f;
#pragma unroll
    for (int j = 0; j < 4; ++j) {
      float v = ad_[i][hd] + as_[j][hd];
      v = v > 0.f ? v : 0.2f * v;
      e[j] = v; mx = fmaxf(mx, v);
    }
    float s = 0.f;
#pragma unroll
    for (int j = 0; j < 4; ++j) { e[j] = __expf(e[j] - mx); s += e[j]; }
    const float inv = 1.0f / s;
#pragma unroll
    for (int j = 0; j < 4; ++j) alpha[i][hd][j] = e[j] * inv;
  }
  __syncthreads();

  // aggregate + gat_bias + residual, then LayerNorm over 768 (wave-local)
  const int i = w;
  float v[12];
  float mean = 0.f;
#pragma unroll
  for (int c0 = 0; c0 < 12; ++c0) {
    const int c = c0 * 64 + lane;
    const int hd = c / 192;
    float o = alpha[i][hd][0] * hs[c]        + alpha[i][hd][1] * hs[768 + c] +
              alpha[i][hd][2] * hs[1536 + c] + alpha[i][hd][3] * hs[2304 + c];
    o += gbias[c] + xres[base + i * 768 + c];
    v[c0] = o; mean += o;
  }
  mean = wave_sum(mean) * (1.0f / 768.0f);
  float var = 0.f;
#pragma unroll
  for (int c0 = 0; c0 < 12; ++c0) { const float d = v[c0] - mean; var += d * d; }
  var = wave_sum(var) * (1.0f / 768.0f);
  const float inv = rsqrtf(var + 1e-5f);
#pragma unroll
  for (int c0 = 0; c0 < 12; ++c0) {
    const int c = c0 * 64 + lane;
    const float y = (v[c0] - mean) * inv * gamma[c] + beta[c];
    const size_t idx = base + i * 768 + c;
    xout[idx] = y;
    xb[idx] = f2bf(y);
  }
}

// ---------------------------------------------------------------------------
// x = LN(ffn + x). One wave per row (768). Optionally emit bf16 copy.
// Safe when ffn aliases xout (per-thread read-before-write, same indices).
// ---------------------------------------------------------------------------
__global__ __launch_bounds__(256, 4)
void ffn_ln(const float* __restrict__ ffn, const float* __restrict__ xres,
            const float* __restrict__ gamma, const float* __restrict__ beta,
            float* __restrict__ xout, uint16_t* __restrict__ xb, int write_xb) {
  const int t = threadIdx.x, w = t >> 6, lane = t & 63;
  const size_t row = (size_t)blockIdx.x * 4 + w;
  const size_t base = row * 768;
  const float4* fg = (const float4*)(ffn + base);
  const float4* xg = (const float4*)(xres + base);
  float4 v[3];
  float mean = 0.f;
#pragma unroll
  for (int k = 0; k < 3; ++k) {
    const int i = k * 64 + lane;
    const float4 a = fg[i], b = xg[i];
    v[k].x = a.x + b.x; v[k].y = a.y + b.y; v[k].z = a.z + b.z; v[k].w = a.w + b.w;
    mean += v[k].x + v[k].y + v[k].z + v[k].w;
  }
  mean = wave_sum(mean) * (1.0f / 768.0f);
  float var = 0.f;
#pragma unroll
  for (int k = 0; k < 3; ++k) {
    const float dx = v[k].x - mean, dy = v[k].y - mean;
    const float dz = v[k].z - mean, dw = v[k].w - mean;
    var += dx * dx + dy * dy + dz * dz + dw * dw;
  }
  var = wave_sum(var) * (1.0f / 768.0f);
  const float inv = rsqrtf(var + 1e-5f);
#pragma unroll
  for (int k = 0; k < 3; ++k) {
    const int i = k * 64 + lane;
    const float4 g = ((const float4*)gamma)[i], bb = ((const float4*)beta)[i];
    float4 y;
    y.x = (v[k].x - mean) * inv * g.x + bb.x;
    y.y = (v[k].y - mean) * inv * g.y + bb.y;
    y.z = (v[k].z - mean) * inv * g.z + bb.z;
    y.w = (v[k].w - mean) * inv * g.w + bb.w;
    ((float4*)(xout + base))[i] = y;
    if (write_xb) {
      ushort4 p; p.x = f2bf(y.x); p.y = f2bf(y.y); p.z = f2bf(y.z); p.w = f2bf(y.w);
      ((ushort4*)(xb + base))[i] = p;
    }
  }
}

// ---------------------------------------------------------------------------
extern "C" void kernel_launch(void* const* d_in, const int* in_sizes, int n_in,
                              void* d_out, int out_size, void* d_ws, size_t ws_size,
                              hipStream_t stream) {
  const float* img   = (const float*)d_in[0];
  const float* te    = (const float*)d_in[1];
  const float* Wgat  = (const float*)d_in[2];
  const float* asrc  = (const float*)d_in[3];
  const float* adst  = (const float*)d_in[4];
  const float* gbias = (const float*)d_in[5];
  const float* gam   = (const float*)d_in[6];
  const float* bet   = (const float*)d_in[7];
  const float* W1    = (const float*)d_in[8];
  const float* b1    = (const float*)d_in[9];
  const float* W2    = (const float*)d_in[10];
  const float* b2    = (const float*)d_in[11];

  const int B = 16384;
  const size_t ROWS = (size_t)B * 4;        // 65536
  const size_t XE = ROWS * 768;             // 50331648

  // g_f32 (GAT-proj h / FFN output scratch) lives in d_out: the final ffn_ln
  // reads ffn==d_out and writes xout==d_out element-wise (safe), and every
  // earlier use is fully overwritten downstream.
  float* g_f32 = (float*)d_out;

  uint8_t* p = (uint8_t*)d_ws;
  float*    x_f32 = (float*)p;    p += XE * 4;               // 201MB
  uint16_t* xb    = (uint16_t*)p; p += XE * 2;               // 101MB bf16 acts
  uint16_t* mid   = (uint16_t*)p; p += ROWS * 1536 * 2;      // 201MB FFN hidden
  uint16_t* wtg   = (uint16_t*)p; p += (size_t)3 * 768 * 768 * 2;
  uint16_t* wt1   = (uint16_t*)p; p += (size_t)3 * 1536 * 768 * 2;
  uint16_t* wt2   = (uint16_t*)p; p += (size_t)3 * 768 * 1536 * 2;

  // --- per-launch weight prep (small; batched over layers) ---
  transpose_f32_to_bf16<<<dim3(24, 24, 3), 256, 0, stream>>>(Wgat, wtg, 768, 768);
  transpose_f32_to_bf16<<<dim3(48, 24, 3), 256, 0, stream>>>(W1,   wt1, 768, 1536);
  transpose_f32_to_bf16<<<dim3(24, 48, 3), 256, 0, stream>>>(W2,   wt2, 1536, 768);
  init_x<<<2048, 256, 0, stream>>>(img, te, x_f32, xb, (int)(XE / 4));

  for (int l = 0; l < 3; ++l) {
    // h = x @ W_gat[l]   (no bias; GATConv bias applied after aggregation)
    gemm_bf16<0><<<dim3(768 / 128, ROWS / 128), 256, 0, stream>>>(
        xb, wtg + (size_t)l * 768 * 768, nullptr, g_f32, (int)ROWS, 768, 768);
    // attention + gat_bias + residual + LN -> x (f32 + bf16)
    gat_attn_ln<<<B, 256, 0, stream>>>(
        g_f32, x_f32, asrc + l * 768, adst + l * 768, gbias + l * 768,
        gam + l * 768, bet + l * 768, x_f32, xb);
    // mid = relu(x @ W1[l] + b1[l])  (bf16)
    gemm_bf16<1><<<dim3(1536 / 128, ROWS / 128), 256, 0, stream>>>(
        xb, wt1 + (size_t)l * 1536 * 768, b1 + l * 1536, mid, (int)ROWS, 1536, 768);
    // ffn = mid @ W2[l] + b2[l]      (f32)
    gemm_bf16<0><<<dim3(768 / 128, ROWS / 128), 256, 0, stream>>>(
        mid, wt2 + (size_t)l * 768 * 1536, b2 + l * 768, g_f32, (int)ROWS, 768, 1536);
    // x = LN(ffn + x); last layer writes d_out (aliased with g_f32: safe)
    float* xo = (l == 2) ? (float*)d_out : x_f32;
    ffn_ln<<<ROWS / 4, 256, 0, stream>>>(
        g_f32, x_f32, gam + l * 768, bet + l * 768, xo, xb, (l == 2) ? 0 : 1);
  }
}

// Round 4
// 2716.406 us; speedup vs baseline: 1.1757x; 1.0774x over previous
//
#include <hip/hip_runtime.h>
#include <stdint.h>

// ---------------------------------------------------------------------------
// ImageFeatureEncoder: 3 x (GAT over fully-connected 4-node graph + LN + FFN)
// B=16384, N=4, H=768, HEADS=4, OUT=192, L=3.
// R2: T1 chunked XCD swizzle (FETCH 659->103MB, proven).
// R3: GEMM rewritten to 256x256 8-phase structure (T2 swizzle + T3/T4 counted
//     vmcnt + T5 setprio): BK=64, 8 waves 2Mx4N, 128KB LDS dbuf, snake
//     quadrant order, stage-at-ph1 / vmcnt-at-ph4 (~3 phases of HBM cover).
//     R3 counters showed old structure latency-bound: MFMA 28%, HBM 16%.
// ---------------------------------------------------------------------------

typedef __bf16 bf16x8 __attribute__((ext_vector_type(8)));
typedef float  f32x4  __attribute__((ext_vector_type(4)));

__device__ __forceinline__ uint16_t f2bf(float f) {
  union { float f; uint32_t u; } v; v.f = f;
  uint32_t r = v.u + 0x7fffu + ((v.u >> 16) & 1u);   // RNE
  return (uint16_t)(r >> 16);
}

__device__ __forceinline__ float wave_sum(float v) {
#pragma unroll
  for (int off = 32; off > 0; off >>= 1) v += __shfl_xor(v, off);
  return v;
}

__device__ __forceinline__ void gload_lds16(const void* g, void* l) {
  __builtin_amdgcn_global_load_lds(
      (const __attribute__((address_space(1))) void*)(g),
      (__attribute__((address_space(3))) void*)(l), 16, 0, 0);
}

// ---------------------------------------------------------------------------
// 256x256 8-phase GEMM: C[M,N] = A[M,K](bf16 rm) * Bt[N,K](bf16 rm = B^T)
// EPI 0: C float = acc + bias (bias may be null);  EPI 1: C bf16 = relu(+bias)
// 512 thr = 8 waves (2M x 4N); per-wave C = 128x64 = 8x4 frags of 16x16.
// LDS 128KB: A dbuf 2x32KB + B dbuf 2x32KB; tile rows 256 x 64 k-elems.
// T2 swizzle: 16B-block index ^= (row&7); applied on global SOURCE at stage
// (gload_lds dest linear, rule #21) and on ds_read address. row&7 == fr&7 for
// all fragment reads (row offsets are multiples of 8), so XOR term is uniform.
// ---------------------------------------------------------------------------
template <int EPI>
__global__ __launch_bounds__(512, 1)
void gemm256_bf16(const uint16_t* __restrict__ A, const uint16_t* __restrict__ Bt,
                  const float* __restrict__ bias, void* __restrict__ Cv,
                  int M, int N, int K) {
  extern __shared__ uint16_t lds[];  // [A0|A1|B0|B1], 16384 elems (32KB) each

  // T1 chunked XCD swizzle (all grids here have nwg % 8 == 0 -> bijective)
  int wgid = blockIdx.y * gridDim.x + blockIdx.x;
  const int nwg = gridDim.x * gridDim.y;
  wgid = (wgid & 7) * (nwg >> 3) + (wgid >> 3);
  const int bn = wgid % gridDim.x, bm = wgid / gridDim.x;

  const int t = threadIdx.x;
  const int w = t >> 6, lane = t & 63;
  const int wm = w >> 2, wn = w & 3;          // 2M x 4N wave grid
  const int fr = lane & 15, kg = lane >> 4;   // fragment row / k-group
  const int frx = fr & 7;                     // T2 read-side XOR term
  const int rl = lane >> 3;                   // stage: row within 8-row strip
  const int sblk = (lane & 7) ^ rl;           // T2 inverse-swizzled src block

  // stage base: wave w strips rows {w*8 + j*64}, lane covers row +rl, block sblk
  const uint16_t* Ag = A  + (size_t)(bm * 256 + w * 8 + rl) * K + sblk * 8;
  const uint16_t* Bg = Bt + (size_t)(bn * 256 + w * 8 + rl) * K + sblk * 8;

  f32x4 acc[8][4] = {};
  bf16x8 a[4][2], b[2][2];

#define STAGE(CO, DA, DB)                                                     \
  do {                                                                        \
    _Pragma("unroll") for (int j = 0; j < 4; ++j) {                           \
      gload_lds16(Ag + (size_t)(j * 64) * K + (CO), (DA) + (w * 8 + j * 64) * 64); \
      gload_lds16(Bg + (size_t)(j * 64) * K + (CO), (DB) + (w * 8 + j * 64) * 64); \
    }                                                                         \
  } while (0)

#define LOADA(MH)                                                             \
  do {                                                                        \
    _Pragma("unroll") for (int fm = 0; fm < 4; ++fm) {                        \
      const int rowA = wm * 128 + (MH)*64 + fm * 16 + fr;                     \
      a[fm][0] = *(const bf16x8*)&ldsA[rowA * 64 + ((kg) ^ frx) * 8];         \
      a[fm][1] = *(const bf16x8*)&ldsA[rowA * 64 + ((4 + kg) ^ frx) * 8];     \
    }                                                                         \
  } while (0)

#define LOADB(NH)                                                             \
  do {                                                                        \
    _Pragma("unroll") for (int fn = 0; fn < 2; ++fn) {                        \
      const int rowB = wn * 64 + (NH)*32 + fn * 16 + fr;                      \
      b[fn][0] = *(const bf16x8*)&ldsB[rowB * 64 + ((kg) ^ frx) * 8];         \
      b[fn][1] = *(const bf16x8*)&ldsB[rowB * 64 + ((4 + kg) ^ frx) * 8];     \
    }                                                                         \
  } while (0)

#define MFMA_Q(MH, NH)                                                        \
  do {                                                                        \
    _Pragma("unroll") for (int fm = 0; fm < 4; ++fm)                          \
    _Pragma("unroll") for (int fn = 0; fn < 2; ++fn)                          \
    _Pragma("unroll") for (int ks = 0; ks < 2; ++ks)                          \
      acc[(MH)*4 + fm][(NH)*2 + fn] = __builtin_amdgcn_mfma_f32_16x16x32_bf16( \
          a[fm][ks], b[fn][ks], acc[(MH)*4 + fm][(NH)*2 + fn], 0, 0, 0);      \
  } while (0)

#define BAR __builtin_amdgcn_s_barrier()
#define PRIO1 __builtin_amdgcn_s_setprio(1)
#define PRIO0 __builtin_amdgcn_s_setprio(0)

  const int KT = K >> 6;

  // prologue: stage K-tile 0 into buf 0, drain, barrier
  STAGE(0, lds, lds + 32768);
  asm volatile("s_waitcnt vmcnt(0)" ::: "memory");
  BAR;

  for (int kt = 0; kt < KT; ++kt) {
    const uint16_t* ldsA = lds + (kt & 1) * 16384;
    const uint16_t* ldsB = lds + 32768 + (kt & 1) * 16384;
    const bool st = (kt + 1 < KT);

    // phase 1: read A(lo-half) + B(lo) of current tile; stage ALL of tile kt+1
    LOADA(0);
    LOADB(0);
    if (st) {
      uint16_t* dA = lds + ((kt + 1) & 1) * 16384;
      uint16_t* dB = lds + 32768 + ((kt + 1) & 1) * 16384;
      STAGE((size_t)(kt + 1) * 64, dA, dB);
    }
    BAR; PRIO1; MFMA_Q(0, 0); PRIO0; BAR;
    // phase 2: reuse a, load B(hi)
    LOADB(1);
    BAR; PRIO1; MFMA_Q(0, 1); PRIO0; BAR;
    // phase 3: reuse b, load A(hi-half)
    LOADA(1);
    BAR; PRIO1; MFMA_Q(1, 1); PRIO0; BAR;
    // phase 4: reuse a, re-load B(lo); counted wait covers tile kt+1 (staged
    // ~3 phases (~1900cy) ago vs ~900cy HBM latency -> near-free)
    LOADB(0);
    BAR; PRIO1; MFMA_Q(1, 0); PRIO0;
    if (st) asm volatile("s_waitcnt vmcnt(0)" ::: "memory");
    BAR;
  }

#undef STAGE
#undef LOADA
#undef LOADB
#undef MFMA_Q
#undef BAR
#undef PRIO1
#undef PRIO0

  // epilogue: C/D layout col=lane&15, row=(lane>>4)*4+j  [m89/m91-verified]
  const int row0 = bm * 256 + wm * 128 + (lane >> 4) * 4;
  const int col0 = bn * 256 + wn * 64 + fr;
#pragma unroll
  for (int mf = 0; mf < 8; ++mf) {
#pragma unroll
    for (int nf = 0; nf < 4; ++nf) {
      const int col = col0 + nf * 16;
      const float bv = bias ? bias[col] : 0.0f;
#pragma unroll
      for (int jj = 0; jj < 4; ++jj) {
        const int row = row0 + mf * 16 + jj;
        const float v = acc[mf][nf][jj] + bv;
        if (EPI == 0) ((float*)Cv)[(size_t)row * N + col] = v;
        else ((uint16_t*)Cv)[(size_t)row * N + col] = f2bf(fmaxf(v, 0.0f));
      }
    }
  }
}

// ---------------------------------------------------------------------------
// Weight prep: Wt[l][C][R] = bf16(W[l][R][C]); layers batched via blockIdx.z
// ---------------------------------------------------------------------------
__global__ __launch_bounds__(256)
void transpose_f32_to_bf16(const float* __restrict__ W, uint16_t* __restrict__ Wt,
                           int R, int C) {
  __shared__ float tile[32][33];
  const size_t lofs = (size_t)blockIdx.z * R * C;
  W += lofs; Wt += lofs;
  const int c0 = blockIdx.x * 32, r0 = blockIdx.y * 32;
  const int t = threadIdx.x, tc = t & 31, tr = t >> 5;  // tr 0..7
#pragma unroll
  for (int i = 0; i < 4; ++i)
    tile[tr + i * 8][tc] = W[(size_t)(r0 + tr + i * 8) * C + c0 + tc];
  __syncthreads();
#pragma unroll
  for (int i = 0; i < 4; ++i)
    Wt[(size_t)(c0 + tr + i * 8) * R + r0 + tc] = f2bf(tile[tc][tr + i * 8]);
}

// ---------------------------------------------------------------------------
// x = image_features + type_emb ; write f32 and bf16 copies
// ---------------------------------------------------------------------------
__global__ __launch_bounds__(256)
void init_x(const float* __restrict__ img, const float* __restrict__ te,
            float* __restrict__ xout, uint16_t* __restrict__ xb, int n4) {
  for (int i = blockIdx.x * 256 + threadIdx.x; i < n4; i += gridDim.x * 256) {
    const float4 a = ((const float4*)img)[i];
    const float4 b = ((const float4*)te)[i % 768];  // te = 3072 floats = 768 float4
    float4 o; o.x = a.x + b.x; o.y = a.y + b.y; o.z = a.z + b.z; o.w = a.w + b.w;
    ((float4*)xout)[i] = o;
    ushort4 p; p.x = f2bf(o.x); p.y = f2bf(o.y); p.z = f2bf(o.z); p.w = f2bf(o.w);
    ((ushort4*)xb)[i] = p;
  }
}

// ---------------------------------------------------------------------------
// GAT attention (dense 4-node graph) + gat_bias + residual + LayerNorm.
// One block per batch element b. Wave w owns node w.
// ---------------------------------------------------------------------------
__global__ __launch_bounds__(256, 4)
void gat_attn_ln(const float* __restrict__ h, const float* __restrict__ xres,
                 const float* __restrict__ att_src, const float* __restrict__ att_dst,
                 const float* __restrict__ gbias, const float* __restrict__ gamma,
                 const float* __restrict__ beta, float* __restrict__ xout,
                 uint16_t* __restrict__ xb) {
  __shared__ float hs[4 * 768];
  __shared__ float as_[4][4], ad_[4][4];     // [node][head]
  __shared__ float alpha[4][4][4];           // [i][head][j]
  const int b = blockIdx.x;
  const int t = threadIdx.x, w = t >> 6, lane = t & 63;
  const size_t base = (size_t)b * 3072;

  {  // load h[b] : 3072 floats = 768 float4
    const float4* hg = (const float4*)(h + base);
    float4* hl = (float4*)hs;
    for (int i = t; i < 768; i += 256) hl[i] = hg[i];
  }
  __syncthreads();

  {  // per-node, per-head attention dots (length-192 each)
    const int n = w;
#pragma unroll
    for (int hd = 0; hd < 4; ++hd) {
      float ps = 0.f, pd = 0.f;
      for (int d = lane; d < 192; d += 64) {
        const float hv = hs[n * 768 + hd * 192 + d];
        ps += hv * att_src[hd * 192 + d];
        pd += hv * att_dst[hd * 192 + d];
      }
      ps = wave_sum(ps); pd = wave_sum(pd);
      if (lane == 0) { as_[n][hd] = ps; ad_[n][hd] = pd; }
    }
  }
  __syncthreads();

  if (t < 16) {  // alpha[i][hd][:] = softmax_j(leaky_relu(a_d[i]+a_s[j], 0.2))
    const int i = t >> 2, hd = t & 3;
    float e[4], mx = -1e30f;
#pragma unroll
    for (int j = 0; j < 4; ++j) {
      float v = ad_[i][hd] + as_[j][hd];
      v = v > 0.f ? v : 0.2f * v;
      e[j] = v; mx = fmaxf(mx, v);
    }
    float s = 0.f;
#pragma unroll
    for (int j = 0; j < 4; ++j) { e[j] = __expf(e[j] - mx); s += e[j]; }
    const float inv = 1.0f / s;
#pragma unroll
    for (int j = 0; j < 4; ++j) alpha[i][hd][j] = e[j] * inv;
  }
  __syncthreads();

  // aggregate + gat_bias + residual, then LayerNorm over 768 (wave-local)
  const int i = w;
  float v[12];
  float mean = 0.f;
#pragma unroll
  for (int c0 = 0; c0 < 12; ++c0) {
    const int c = c0 * 64 + lane;
    const int hd = c / 192;
    float o = alpha[i][hd][0] * hs[c]        + alpha[i][hd][1] * hs[768 + c] +
              alpha[i][hd][2] * hs[1536 + c] + alpha[i][hd][3] * hs[2304 + c];
    o += gbias[c] + xres[base + i * 768 + c];
    v[c0] = o; mean += o;
  }
  mean = wave_sum(mean) * (1.0f / 768.0f);
  float var = 0.f;
#pragma unroll
  for (int c0 = 0; c0 < 12; ++c0) { const float d = v[c0] - mean; var += d * d; }
  var = wave_sum(var) * (1.0f / 768.0f);
  const float inv = rsqrtf(var + 1e-5f);
#pragma unroll
  for (int c0 = 0; c0 < 12; ++c0) {
    const int c = c0 * 64 + lane;
    const float y = (v[c0] - mean) * inv * gamma[c] + beta[c];
    const size_t idx = base + i * 768 + c;
    xout[idx] = y;
    xb[idx] = f2bf(y);
  }
}

// ---------------------------------------------------------------------------
// x = LN(ffn + x). One wave per row (768). Optionally emit bf16 copy.
// Safe when ffn aliases xout (per-thread read-before-write, same indices).
// ---------------------------------------------------------------------------
__global__ __launch_bounds__(256, 4)
void ffn_ln(const float* __restrict__ ffn, const float* __restrict__ xres,
            const float* __restrict__ gamma, const float* __restrict__ beta,
            float* __restrict__ xout, uint16_t* __restrict__ xb, int write_xb) {
  const int t = threadIdx.x, w = t >> 6, lane = t & 63;
  const size_t row = (size_t)blockIdx.x * 4 + w;
  const size_t base = row * 768;
  const float4* fg = (const float4*)(ffn + base);
  const float4* xg = (const float4*)(xres + base);
  float4 v[3];
  float mean = 0.f;
#pragma unroll
  for (int k = 0; k < 3; ++k) {
    const int i = k * 64 + lane;
    const float4 a = fg[i], b = xg[i];
    v[k].x = a.x + b.x; v[k].y = a.y + b.y; v[k].z = a.z + b.z; v[k].w = a.w + b.w;
    mean += v[k].x + v[k].y + v[k].z + v[k].w;
  }
  mean = wave_sum(mean) * (1.0f / 768.0f);
  float var = 0.f;
#pragma unroll
  for (int k = 0; k < 3; ++k) {
    const float dx = v[k].x - mean, dy = v[k].y - mean;
    const float dz = v[k].z - mean, dw = v[k].w - mean;
    var += dx * dx + dy * dy + dz * dz + dw * dw;
  }
  var = wave_sum(var) * (1.0f / 768.0f);
  const float inv = rsqrtf(var + 1e-5f);
#pragma unroll
  for (int k = 0; k < 3; ++k) {
    const int i = k * 64 + lane;
    const float4 g = ((const float4*)gamma)[i], bb = ((const float4*)beta)[i];
    float4 y;
    y.x = (v[k].x - mean) * inv * g.x + bb.x;
    y.y = (v[k].y - mean) * inv * g.y + bb.y;
    y.z = (v[k].z - mean) * inv * g.z + bb.z;
    y.w = (v[k].w - mean) * inv * g.w + bb.w;
    ((float4*)(xout + base))[i] = y;
    if (write_xb) {
      ushort4 p; p.x = f2bf(y.x); p.y = f2bf(y.y); p.z = f2bf(y.z); p.w = f2bf(y.w);
      ((ushort4*)(xb + base))[i] = p;
    }
  }
}

// ---------------------------------------------------------------------------
extern "C" void kernel_launch(void* const* d_in, const int* in_sizes, int n_in,
                              void* d_out, int out_size, void* d_ws, size_t ws_size,
                              hipStream_t stream) {
  const float* img   = (const float*)d_in[0];
  const float* te    = (const float*)d_in[1];
  const float* Wgat  = (const float*)d_in[2];
  const float* asrc  = (const float*)d_in[3];
  const float* adst  = (const float*)d_in[4];
  const float* gbias = (const float*)d_in[5];
  const float* gam   = (const float*)d_in[6];
  const float* bet   = (const float*)d_in[7];
  const float* W1    = (const float*)d_in[8];
  const float* b1    = (const float*)d_in[9];
  const float* W2    = (const float*)d_in[10];
  const float* b2    = (const float*)d_in[11];

  const int B = 16384;
  const size_t ROWS = (size_t)B * 4;        // 65536
  const size_t XE = ROWS * 768;             // 50331648

  // allow 128KB dynamic LDS for the GEMM kernels (idempotent, host-side)
  (void)hipFuncSetAttribute(reinterpret_cast<const void*>(&gemm256_bf16<0>),
                            hipFuncAttributeMaxDynamicSharedMemorySize, 131072);
  (void)hipFuncSetAttribute(reinterpret_cast<const void*>(&gemm256_bf16<1>),
                            hipFuncAttributeMaxDynamicSharedMemorySize, 131072);

  // g_f32 (GAT-proj h / FFN output scratch) lives in d_out: the final ffn_ln
  // reads ffn==d_out and writes xout==d_out element-wise (safe), and every
  // earlier use is fully overwritten downstream.
  float* g_f32 = (float*)d_out;

  uint8_t* p = (uint8_t*)d_ws;
  float*    x_f32 = (float*)p;    p += XE * 4;               // 201MB
  uint16_t* xb    = (uint16_t*)p; p += XE * 2;               // 101MB bf16 acts
  uint16_t* mid   = (uint16_t*)p; p += ROWS * 1536 * 2;      // 201MB FFN hidden
  uint16_t* wtg   = (uint16_t*)p; p += (size_t)3 * 768 * 768 * 2;
  uint16_t* wt1   = (uint16_t*)p; p += (size_t)3 * 1536 * 768 * 2;
  uint16_t* wt2   = (uint16_t*)p; p += (size_t)3 * 768 * 1536 * 2;

  // --- per-launch weight prep (small; batched over layers) ---
  transpose_f32_to_bf16<<<dim3(24, 24, 3), 256, 0, stream>>>(Wgat, wtg, 768, 768);
  transpose_f32_to_bf16<<<dim3(48, 24, 3), 256, 0, stream>>>(W1,   wt1, 768, 1536);
  transpose_f32_to_bf16<<<dim3(24, 48, 3), 256, 0, stream>>>(W2,   wt2, 1536, 768);
  init_x<<<2048, 256, 0, stream>>>(img, te, x_f32, xb, (int)(XE / 4));

  for (int l = 0; l < 3; ++l) {
    // h = x @ W_gat[l]   (no bias; GATConv bias applied after aggregation)
    gemm256_bf16<0><<<dim3(768 / 256, ROWS / 256), 512, 131072, stream>>>(
        xb, wtg + (size_t)l * 768 * 768, nullptr, g_f32, (int)ROWS, 768, 768);
    // attention + gat_bias + residual + LN -> x (f32 + bf16)
    gat_attn_ln<<<B, 256, 0, stream>>>(
        g_f32, x_f32, asrc + l * 768, adst + l * 768, gbias + l * 768,
        gam + l * 768, bet + l * 768, x_f32, xb);
    // mid = relu(x @ W1[l] + b1[l])  (bf16)
    gemm256_bf16<1><<<dim3(1536 / 256, ROWS / 256), 512, 131072, stream>>>(
        xb, wt1 + (size_t)l * 1536 * 768, b1 + l * 1536, mid, (int)ROWS, 1536, 768);
    // ffn = mid @ W2[l] + b2[l]      (f32)
    gemm256_bf16<0><<<dim3(768 / 256, ROWS / 256), 512, 131072, stream>>>(
        mid, wt2 + (size_t)l * 768 * 1536, b2 + l * 768, g_f32, (int)ROWS, 768, 1536);
    // x = LN(ffn + x); last layer writes d_out (aliased with g_f32: safe)
    float* xo = (l == 2) ? (float*)d_out : x_f32;
    ffn_ln<<<ROWS / 4, 256, 0, stream>>>(
        g_f32, x_f32, gam + l * 768, bet + l * 768, xo, xb, (l == 2) ? 0 : 1);
  }
}